// Round 8
// baseline (90.422 us; speedup 1.0000x reference)
//
#include <hip/hip_runtime.h>
#include <hip/hip_bf16.h>
#include <math.h>

#define B_ 2
#define C_ 256
#define H_ 64
#define W_ 64
#define L_ 4096
#define HEADS_ 8
#define DH_ 32
#define CG_ 8
#define K_ 7
#define PAD_ 3
#define K2_ 49
#define PW_ 70
#define PPIX_ 4900
#define PADT4_ ((size_t)B_*HEADS_*CG_*PPIX_)   // 627200 float4 per padded tensor
#define WS_STR 72                               // LDS row stride in bf16 (144B, 16B-aligned)

typedef short bf16x8 __attribute__((ext_vector_type(8)));
typedef float f32x4  __attribute__((ext_vector_type(4)));

__device__ inline unsigned short f2bf(float f) {
    union { float f; unsigned u; } uf; uf.f = f;
    unsigned r = uf.u + 0x7fffu + ((uf.u >> 16) & 1u);   // RNE
    return (unsigned short)(r >> 16);
}
__device__ inline unsigned pk2(float a, float b) {
    return (unsigned)f2bf(a) | ((unsigned)f2bf(b) << 16);
}

// ---------------- Kernel A: weight pack (bf16) + K/V halo zero, one launch --
__global__ __launch_bounds__(256) void prep(
    const float* __restrict__ wq, const float* __restrict__ wk,
    const float* __restrict__ wv, const float* __restrict__ wo,
    unsigned* __restrict__ wb, float4* __restrict__ kt, float4* __restrict__ vt)
{
    const int bidx = blockIdx.x;
    if (bidx < 512) {
        int idx = bidx*256 + threadIdx.x;   // 0..131071
        const float* src = (idx < 32768) ? wq : (idx < 65536) ? wk : (idx < 98304) ? wv : wo;
        int off = (idx & 32767) * 2;
        wb[idx] = pk2(src[off], src[off+1]);
    } else {
        int idx = (bidx - 512)*256 + threadIdx.x;
        if (idx >= (int)PADT4_) return;
        int cell = idx % PPIX_;
        int px = cell % PW_, py = cell / PW_;
        if (px < PAD_ || px >= PW_-PAD_ || py < PAD_ || py >= PW_-PAD_) {
            float4 z = make_float4(0.f,0.f,0.f,0.f);
            kt[idx] = z;
            vt[idx] = z;
        }
    }
}

// ---------------- Kernel B: QKV projection via bf16 MFMA (128-o tiles) ------
// Block: 128 o x 64 l (one image row). grid (64, 2, 6) = 768 blocks.
__global__ __launch_bounds__(256) void qkv_mfma(
    const float* __restrict__ q_in, const float* __restrict__ k_in, const float* __restrict__ v_in,
    const unsigned* __restrict__ wb,
    const float* __restrict__ bq, const float* __restrict__ bk, const float* __restrict__ bv,
    float4* __restrict__ qt4, float4* __restrict__ kt4, float4* __restrict__ vt4)
{
    const int z = blockIdx.z;
    const int which = z >> 1;      // 0=q,1=k,2=v
    const int b = z & 1;
    const float* X = (which==0) ? q_in : (which==1 ? k_in : v_in);
    const unsigned* wbp = wb + which*32768;
    const float* bias = (which==0) ? bq : (which==1 ? bk : bv);

    const int y    = blockIdx.x;
    const int l0   = y * 64;
    const int o_t0 = blockIdx.y * 128;
    const int tid  = threadIdx.x;
    const int lane = tid & 63, wave = tid >> 6;
    const int orow = lane & 15, kgrp = lane >> 4;

    __shared__ short Ws[128*WS_STR];   // weights [o][c-chunk]  (18.4 KB)
    __shared__ short Xs[64*WS_STR];    // input^T [l][c-chunk]  (9.2 KB)

    f32x4 acc[2][4] = {};
    const int cq  = tid >> 6;
    const int lst = tid & 63;

    for (int ch = 0; ch < 4; ++ch) {
        const int c0 = ch*64;
        #pragma unroll
        for (int i = 0; i < 8; ++i) {
            int o  = i*16 + (tid>>4);
            int c4 = tid & 15;
            uint2 v = *reinterpret_cast<const uint2*>(wbp + (size_t)(o_t0 + o)*128 + (c0>>1) + c4*2);
            *reinterpret_cast<uint2*>(&Ws[o*WS_STR + c4*4]) = v;
        }
        #pragma unroll
        for (int i = 0; i < 8; ++i) {
            int cc = cq*2 + i*8;
            float a  = X[(size_t)(b*C_ + c0 + cc    )*L_ + l0 + lst];
            float b2 = X[(size_t)(b*C_ + c0 + cc + 1)*L_ + l0 + lst];
            *reinterpret_cast<unsigned*>(&Xs[lst*WS_STR + cc]) = pk2(a, b2);
        }
        __syncthreads();
        #pragma unroll
        for (int kk = 0; kk < 2; ++kk) {
            bf16x8 af[2], bfr[4];
            #pragma unroll
            for (int fo = 0; fo < 2; ++fo)
                af[fo] = *reinterpret_cast<const bf16x8*>(&Ws[(wave*32 + fo*16 + orow)*WS_STR + kk*32 + kgrp*8]);
            #pragma unroll
            for (int fn = 0; fn < 4; ++fn)
                bfr[fn] = *reinterpret_cast<const bf16x8*>(&Xs[(fn*16 + orow)*WS_STR + kk*32 + kgrp*8]);
            #pragma unroll
            for (int fo = 0; fo < 2; ++fo)
                #pragma unroll
                for (int fn = 0; fn < 4; ++fn)
                    acc[fo][fn] = __builtin_amdgcn_mfma_f32_16x16x32_bf16(af[fo], bfr[fn], acc[fo][fn], 0, 0, 0);
        }
        __syncthreads();
    }

    #pragma unroll
    for (int fo = 0; fo < 2; ++fo) {
        const int og = o_t0 + wave*32 + fo*16 + kgrp*4;
        const float4 b4 = *reinterpret_cast<const float4*>(&bias[og]);
        const size_t p = (size_t)(b*64 + (og >> 2));   // plane index
        #pragma unroll
        for (int fn = 0; fn < 4; ++fn) {
            const int xl = fn*16 + orow;
            float4 r;
            r.x = acc[fo][fn][0] + b4.x;
            r.y = acc[fo][fn][1] + b4.y;
            r.z = acc[fo][fn][2] + b4.z;
            r.w = acc[fo][fn][3] + b4.w;
            if (which == 0) {
                qt4[p*L_ + l0 + xl] = r;
            } else {
                float4* dst = (which==1) ? kt4 : vt4;
                dst[p*PPIX_ + (size_t)(y+PAD_)*PW_ + (xl+PAD_)] = r;
            }
        }
    }
}

// ---------------- Kernel C: 7x7 local attention, 8-wave row-pair -----------
// Block = (plane=b*8+h, row-pair y0,y0+1), 512 threads, grid 512.
// QK: wave w -> padded window row y0+w (w=0..7), both pixels, full channel sum;
//     logits -> LDS S[2][49][64].
// Softmax: wave 0 -> pixel 0, wave 1 -> pixel 1; exp'd P written back to S,
//     1/sum -> invs.
// PV: wave w -> channel-group w, both pixels; P read from LDS (2-way = free).
__global__ __launch_bounds__(512) void local_attn(
    float4* __restrict__ qt4, const float4* __restrict__ kt4, const float4* __restrict__ vt4)
{
    const int tid = threadIdx.x;
    const int w = tid >> 6, x = tid & 63;
    const int bid = blockIdx.x;
    const int plane = bid & 15;      // plane p -> XCD p%8 (K/V L2-resident per XCD)
    const int y0 = (bid >> 4) * 2;

    const float4* kb = kt4 + (size_t)plane*CG_*PPIX_;
    const float4* vb = vt4 + (size_t)plane*CG_*PPIX_;
    float4* qpl = qt4 + (size_t)plane*CG_*L_;

    __shared__ float S[2][K2_][64];      // 24.5 KB
    __shared__ float invs[2][64];

    // ---- QK: my window row (y0+w), both pixels ----
    float4 q0[CG_], q1[CG_];
    if (w < 7) {
        #pragma unroll
        for (int cg=0; cg<CG_; ++cg) q0[cg] = qpl[(size_t)cg*L_ + (y0  )*W_ + x];
    }
    if (w > 0) {
        #pragma unroll
        for (int cg=0; cg<CG_; ++cg) q1[cg] = qpl[(size_t)cg*L_ + (y0+1)*W_ + x];
    }

    float lgA[K_] = {};   // pixel y0   (window row w, valid w<7)
    float lgB[K_] = {};   // pixel y0+1 (window row w-1, valid w>0)
    #pragma unroll
    for (int cg=0; cg<CG_; ++cg) {
        const float4* row = kb + (size_t)cg*PPIX_ + (size_t)(y0 + w)*PW_ + x;
        #pragma unroll
        for (int kx=0; kx<K_; ++kx) {
            float4 kv = row[kx];
            if (w < 7) {
                float4 q = q0[cg];
                lgA[kx] = fmaf(q.x,kv.x, fmaf(q.y,kv.y, fmaf(q.z,kv.z, fmaf(q.w,kv.w, lgA[kx]))));
            }
            if (w > 0) {
                float4 q = q1[cg];
                lgB[kx] = fmaf(q.x,kv.x, fmaf(q.y,kv.y, fmaf(q.z,kv.z, fmaf(q.w,kv.w, lgB[kx]))));
            }
        }
    }
    if (w < 7) {
        #pragma unroll
        for (int kx=0; kx<K_; ++kx) S[0][w*K_+kx][x] = lgA[kx];
    }
    if (w > 0) {
        #pragma unroll
        for (int kx=0; kx<K_; ++kx) S[1][(w-1)*K_+kx][x] = lgB[kx];
    }
    __syncthreads();

    // ---- softmax: wave 0 -> pixel 0, wave 1 -> pixel 1 ----
    if (w < 2) {
        const float scale = 0.0625f; // 1/sqrt(256)
        float p[K2_];
        #pragma unroll
        for (int i=0;i<K2_;++i) p[i] = S[w][i][x];
        float m = p[0];
        #pragma unroll
        for (int i=1;i<K2_;++i) m = fmaxf(m, p[i]);
        float sum = 0.f;
        #pragma unroll
        for (int i=0;i<K2_;++i) { p[i] = __expf((p[i]-m)*scale); sum += p[i]; }
        #pragma unroll
        for (int i=0;i<K2_;++i) S[w][i][x] = p[i];
        invs[w][x] = 1.0f/sum;
    }
    __syncthreads();

    // ---- PV: my channel-group (cg = w), both pixels, P from LDS ----
    {
        const int cg = w;
        float4 a0 = make_float4(0.f,0.f,0.f,0.f);
        float4 a1 = make_float4(0.f,0.f,0.f,0.f);
        #pragma unroll
        for (int r=0; r<8; ++r) {
            const float4* row = vb + (size_t)cg*PPIX_ + (size_t)(y0 + r)*PW_ + x;
            #pragma unroll
            for (int kx=0; kx<K_; ++kx) {
                float4 vv = row[kx];
                if (r < 7) {
                    float pp = S[0][r*K_+kx][x];
                    a0.x = fmaf(pp, vv.x, a0.x); a0.y = fmaf(pp, vv.y, a0.y);
                    a0.z = fmaf(pp, vv.z, a0.z); a0.w = fmaf(pp, vv.w, a0.w);
                }
                if (r > 0) {
                    float pp = S[1][(r-1)*K_+kx][x];
                    a1.x = fmaf(pp, vv.x, a1.x); a1.y = fmaf(pp, vv.y, a1.y);
                    a1.z = fmaf(pp, vv.z, a1.z); a1.w = fmaf(pp, vv.w, a1.w);
                }
            }
        }
        const float inv0 = invs[0][x], inv1 = invs[1][x];
        a0.x *= inv0; a0.y *= inv0; a0.z *= inv0; a0.w *= inv0;
        a1.x *= inv1; a1.y *= inv1; a1.z *= inv1; a1.w *= inv1;
        qpl[(size_t)cg*L_ + (y0  )*W_ + x] = a0;
        qpl[(size_t)cg*L_ + (y0+1)*W_ + x] = a1;
    }
}

// ---------------- Kernel D: output projection via bf16 MFMA (64-o tiles) ----
// grid (64, 4, 2) = 512 blocks.
__global__ __launch_bounds__(256) void out_mfma(
    const float4* __restrict__ qt4, const unsigned* __restrict__ wb,
    const float* __restrict__ bo, float* __restrict__ out)
{
    const int b    = blockIdx.z;
    const int l0   = blockIdx.x * 64;
    const int o_t0 = blockIdx.y * 64;
    const unsigned* wbp = wb + 3*32768;
    const int tid  = threadIdx.x;
    const int lane = tid & 63, wave = tid >> 6;
    const int orow = lane & 15, kgrp = lane >> 4;

    __shared__ short Ws[64*WS_STR];    // 9.2 KB
    __shared__ short Xs[64*WS_STR];    // 9.2 KB

    f32x4 acc[4] = {};
    const int cq  = tid >> 6;
    const int lst = tid & 63;

    for (int ch = 0; ch < 4; ++ch) {
        const int c0 = ch*64;
        #pragma unroll
        for (int i = 0; i < 4; ++i) {
            int o  = i*16 + (tid>>4);
            int c4 = tid & 15;
            uint2 v = *reinterpret_cast<const uint2*>(wbp + (size_t)(o_t0 + o)*128 + (c0>>1) + c4*2);
            *reinterpret_cast<uint2*>(&Ws[o*WS_STR + c4*4]) = v;
        }
        #pragma unroll
        for (int i = 0; i < 4; ++i) {
            int c4i = i*4 + cq;
            float4 vv = qt4[(size_t)(b*64 + (c0>>2) + c4i)*L_ + l0 + lst];
            *reinterpret_cast<unsigned*>(&Xs[lst*WS_STR + c4i*4    ]) = pk2(vv.x, vv.y);
            *reinterpret_cast<unsigned*>(&Xs[lst*WS_STR + c4i*4 + 2]) = pk2(vv.z, vv.w);
        }
        __syncthreads();
        #pragma unroll
        for (int kk = 0; kk < 2; ++kk) {
            bf16x8 af, bfr[4];
            af = *reinterpret_cast<const bf16x8*>(&Ws[(wave*16 + orow)*WS_STR + kk*32 + kgrp*8]);
            #pragma unroll
            for (int fn = 0; fn < 4; ++fn)
                bfr[fn] = *reinterpret_cast<const bf16x8*>(&Xs[(fn*16 + orow)*WS_STR + kk*32 + kgrp*8]);
            #pragma unroll
            for (int fn = 0; fn < 4; ++fn)
                acc[fn] = __builtin_amdgcn_mfma_f32_16x16x32_bf16(af, bfr[fn], acc[fn], 0, 0, 0);
        }
        __syncthreads();
    }

    {
        const int o_base = o_t0 + wave*16 + kgrp*4;
        #pragma unroll
        for (int fn = 0; fn < 4; ++fn) {
            const int xl = fn*16 + orow;
            #pragma unroll
            for (int r = 0; r < 4; ++r)
                out[(size_t)(b*C_ + o_base + r)*L_ + l0 + xl] = acc[fn][r] + bo[o_base + r];
        }
    }
}

extern "C" void kernel_launch(void* const* d_in, const int* in_sizes, int n_in,
                              void* d_out, int out_size, void* d_ws, size_t ws_size,
                              hipStream_t stream) {
    const float* queries = (const float*)d_in[0];
    const float* keys    = (const float*)d_in[1];
    const float* values  = (const float*)d_in[2];
    const float* wq = (const float*)d_in[3];
    const float* bq = (const float*)d_in[4];
    const float* wk = (const float*)d_in[5];
    const float* bk = (const float*)d_in[6];
    const float* wv = (const float*)d_in[7];
    const float* bv = (const float*)d_in[8];
    const float* wo = (const float*)d_in[9];
    const float* bo = (const float*)d_in[10];
    float* out = (float*)d_out;

    float4* qt4 = (float4*)d_ws;                           // Q planar-c4, attn out in-place
    float4* kt4 = qt4 + (size_t)B_*HEADS_*CG_*L_;          // padded planar K
    float4* vt4 = kt4 + PADT4_;                            // padded planar V
    unsigned* wb = (unsigned*)(vt4 + PADT4_);              // bf16 packed weights

    const unsigned halo_blocks = (unsigned)((PADT4_ + 255)/256);
    prep<<<512 + halo_blocks, 256, 0, stream>>>(wq, wk, wv, wo, wb, kt4, vt4);
    qkv_mfma<<<dim3(64, 2, 6), 256, 0, stream>>>(queries, keys, values, wb, bq, bk, bv, qt4, kt4, vt4);
    local_attn<<<512, 512, 0, stream>>>(qt4, kt4, vt4);
    out_mfma<<<dim3(64, 4, 2), 256, 0, stream>>>(qt4, wb, bo, out);
}

// Round 9
// 73.724 us; speedup vs baseline: 1.2265x; 1.2265x over previous
//
#include <hip/hip_runtime.h>
#include <hip/hip_bf16.h>
#include <math.h>

#define B_ 2
#define C_ 256
#define H_ 64
#define W_ 64
#define L_ 4096
#define HEADS_ 8
#define DH_ 32
#define CG_ 8
#define K_ 7
#define PAD_ 3
#define K2_ 49
#define PW_ 70
#define PPIX_ 4900
#define PADT4_ ((size_t)B_*HEADS_*CG_*PPIX_)   // 627200 float4 per padded tensor
#define WS_STR 72                               // LDS row stride in bf16 (144B, 16B-aligned)

typedef short bf16x8 __attribute__((ext_vector_type(8)));
typedef float f32x4  __attribute__((ext_vector_type(4)));

__device__ inline unsigned short f2bf(float f) {
    union { float f; unsigned u; } uf; uf.f = f;
    unsigned r = uf.u + 0x7fffu + ((uf.u >> 16) & 1u);   // RNE
    return (unsigned short)(r >> 16);
}
__device__ inline unsigned pk2(float a, float b) {
    return (unsigned)f2bf(a) | ((unsigned)f2bf(b) << 16);
}

// ---------------- Kernel A: weight pack (bf16) + K/V halo zero, one launch --
__global__ __launch_bounds__(256) void prep(
    const float* __restrict__ wq, const float* __restrict__ wk,
    const float* __restrict__ wv, const float* __restrict__ wo,
    unsigned* __restrict__ wb, float4* __restrict__ kt, float4* __restrict__ vt)
{
    const int bidx = blockIdx.x;
    if (bidx < 512) {
        int idx = bidx*256 + threadIdx.x;   // 0..131071
        const float* src = (idx < 32768) ? wq : (idx < 65536) ? wk : (idx < 98304) ? wv : wo;
        int off = (idx & 32767) * 2;
        wb[idx] = pk2(src[off], src[off+1]);
    } else {
        int idx = (bidx - 512)*256 + threadIdx.x;
        if (idx >= (int)PADT4_) return;
        int cell = idx % PPIX_;
        int px = cell % PW_, py = cell / PW_;
        if (px < PAD_ || px >= PW_-PAD_ || py < PAD_ || py >= PW_-PAD_) {
            float4 z = make_float4(0.f,0.f,0.f,0.f);
            kt[idx] = z;
            vt[idx] = z;
        }
    }
}

// ---------------- Kernel B: QKV projection via bf16 MFMA (128-o tiles) ------
// Block: 128 o x 64 l (one image row). grid (64, 2, 6) = 768 blocks.
__global__ __launch_bounds__(256) void qkv_mfma(
    const float* __restrict__ q_in, const float* __restrict__ k_in, const float* __restrict__ v_in,
    const unsigned* __restrict__ wb,
    const float* __restrict__ bq, const float* __restrict__ bk, const float* __restrict__ bv,
    float4* __restrict__ qt4, float4* __restrict__ kt4, float4* __restrict__ vt4)
{
    const int z = blockIdx.z;
    const int which = z >> 1;      // 0=q,1=k,2=v
    const int b = z & 1;
    const float* X = (which==0) ? q_in : (which==1 ? k_in : v_in);
    const unsigned* wbp = wb + which*32768;
    const float* bias = (which==0) ? bq : (which==1 ? bk : bv);

    const int y    = blockIdx.x;
    const int l0   = y * 64;
    const int o_t0 = blockIdx.y * 128;
    const int tid  = threadIdx.x;
    const int lane = tid & 63, wave = tid >> 6;
    const int orow = lane & 15, kgrp = lane >> 4;

    __shared__ short Ws[128*WS_STR];   // weights [o][c-chunk]  (18.4 KB)
    __shared__ short Xs[64*WS_STR];    // input^T [l][c-chunk]  (9.2 KB)

    f32x4 acc[2][4] = {};
    const int cq  = tid >> 6;
    const int lst = tid & 63;

    for (int ch = 0; ch < 4; ++ch) {
        const int c0 = ch*64;
        #pragma unroll
        for (int i = 0; i < 8; ++i) {
            int o  = i*16 + (tid>>4);
            int c4 = tid & 15;
            uint2 v = *reinterpret_cast<const uint2*>(wbp + (size_t)(o_t0 + o)*128 + (c0>>1) + c4*2);
            *reinterpret_cast<uint2*>(&Ws[o*WS_STR + c4*4]) = v;
        }
        #pragma unroll
        for (int i = 0; i < 8; ++i) {
            int cc = cq*2 + i*8;
            float a  = X[(size_t)(b*C_ + c0 + cc    )*L_ + l0 + lst];
            float b2 = X[(size_t)(b*C_ + c0 + cc + 1)*L_ + l0 + lst];
            *reinterpret_cast<unsigned*>(&Xs[lst*WS_STR + cc]) = pk2(a, b2);
        }
        __syncthreads();
        #pragma unroll
        for (int kk = 0; kk < 2; ++kk) {
            bf16x8 af[2], bfr[4];
            #pragma unroll
            for (int fo = 0; fo < 2; ++fo)
                af[fo] = *reinterpret_cast<const bf16x8*>(&Ws[(wave*32 + fo*16 + orow)*WS_STR + kk*32 + kgrp*8]);
            #pragma unroll
            for (int fn = 0; fn < 4; ++fn)
                bfr[fn] = *reinterpret_cast<const bf16x8*>(&Xs[(fn*16 + orow)*WS_STR + kk*32 + kgrp*8]);
            #pragma unroll
            for (int fo = 0; fo < 2; ++fo)
                #pragma unroll
                for (int fn = 0; fn < 4; ++fn)
                    acc[fo][fn] = __builtin_amdgcn_mfma_f32_16x16x32_bf16(af[fo], bfr[fn], acc[fo][fn], 0, 0, 0);
        }
        __syncthreads();
    }

    #pragma unroll
    for (int fo = 0; fo < 2; ++fo) {
        const int og = o_t0 + wave*32 + fo*16 + kgrp*4;
        const float4 b4 = *reinterpret_cast<const float4*>(&bias[og]);
        const size_t p = (size_t)(b*64 + (og >> 2));   // plane index
        #pragma unroll
        for (int fn = 0; fn < 4; ++fn) {
            const int xl = fn*16 + orow;
            float4 r;
            r.x = acc[fo][fn][0] + b4.x;
            r.y = acc[fo][fn][1] + b4.y;
            r.z = acc[fo][fn][2] + b4.z;
            r.w = acc[fo][fn][3] + b4.w;
            if (which == 0) {
                qt4[p*L_ + l0 + xl] = r;
            } else {
                float4* dst = (which==1) ? kt4 : vt4;
                dst[p*PPIX_ + (size_t)(y+PAD_)*PW_ + (xl+PAD_)] = r;
            }
        }
    }
}

// ---------------- Kernel C: 7x7 local attention, 1-row blocks, no reg arrays -
// Block = (plane=b*8+h, image row y), 256 threads (4 waves), grid 1024.
// QK: wave w -> padded window rows {y+w, y+w+4} (w+4 only if w<3), full channel
//     sum; logits -> LDS S[49][64].
// Softmax: NO max subtraction (post-scale logits are ~N(0,0.35) — exp safe in
//     f32, identical math to the max-subtracted reference). Each wave scans S
//     with scalar sum only.
// PV: wave w -> channel-groups {2w, 2w+1}; p = exp(S*scale) recomputed on the
//     fly (no p[] array). Output in-place over Q (block reads only its own row).
__global__ __launch_bounds__(256) void local_attn(
    float4* __restrict__ qt4, const float4* __restrict__ kt4, const float4* __restrict__ vt4)
{
    const int tid = threadIdx.x;
    const int w = tid >> 6, x = tid & 63;
    const int bid = blockIdx.x;
    const int plane = bid & 15;      // b*HEADS_+h ; plane -> XCD p%8 locality
    const int y = bid >> 4;          // 0..63

    const float4* kb = kt4 + (size_t)plane*CG_*PPIX_;
    const float4* vb = vt4 + (size_t)plane*CG_*PPIX_;
    float4* qpl = qt4 + (size_t)plane*CG_*L_;

    __shared__ float S[K2_][64];     // 12.25 KB

    // ---- QK: my window rows r = w and w+4 ----
    float lg[2][K_] = {};
    #pragma unroll
    for (int cg=0; cg<CG_; ++cg) {
        const float4 q = qpl[(size_t)cg*L_ + y*W_ + x];
        #pragma unroll
        for (int rr=0; rr<2; ++rr) {
            const int r = w + rr*4;
            if (r > 6) continue;                  // only w=3,rr=1 skips (uniform)
            const float4* row = kb + (size_t)cg*PPIX_ + (size_t)(y + r)*PW_ + x;
            #pragma unroll
            for (int kx=0; kx<K_; ++kx) {
                float4 kv = row[kx];
                lg[rr][kx] = fmaf(q.x,kv.x, fmaf(q.y,kv.y, fmaf(q.z,kv.z, fmaf(q.w,kv.w, lg[rr][kx]))));
            }
        }
    }
    #pragma unroll
    for (int rr=0; rr<2; ++rr) {
        const int r = w + rr*4;
        if (r <= 6) {
            #pragma unroll
            for (int kx=0; kx<K_; ++kx) S[r*K_+kx][x] = lg[rr][kx];
        }
    }
    __syncthreads();

    const float scale = 0.0625f; // 1/sqrt(256)

    // ---- denominator: scalar scan over S (duplicated per wave; no arrays) ----
    float sum = 0.f;
    #pragma unroll
    for (int i=0;i<K2_;++i) sum += __expf(S[i][x]*scale);
    const float inv = 1.0f/sum;

    // ---- PV: my channel-groups {2w, 2w+1}; exp recomputed per tap ----
    const int cg0 = w*2, cg1 = w*2 + 1;
    float4 a0 = make_float4(0.f,0.f,0.f,0.f);
    float4 a1 = make_float4(0.f,0.f,0.f,0.f);
    #pragma unroll
    for (int r=0; r<K_; ++r) {
        const float4* row0 = vb + (size_t)cg0*PPIX_ + (size_t)(y + r)*PW_ + x;
        const float4* row1 = vb + (size_t)cg1*PPIX_ + (size_t)(y + r)*PW_ + x;
        #pragma unroll
        for (int kx=0; kx<K_; ++kx) {
            const float p = __expf(S[r*K_+kx][x]*scale);
            float4 v0 = row0[kx];
            float4 v1 = row1[kx];
            a0.x = fmaf(p, v0.x, a0.x); a0.y = fmaf(p, v0.y, a0.y);
            a0.z = fmaf(p, v0.z, a0.z); a0.w = fmaf(p, v0.w, a0.w);
            a1.x = fmaf(p, v1.x, a1.x); a1.y = fmaf(p, v1.y, a1.y);
            a1.z = fmaf(p, v1.z, a1.z); a1.w = fmaf(p, v1.w, a1.w);
        }
    }
    a0.x *= inv; a0.y *= inv; a0.z *= inv; a0.w *= inv;
    a1.x *= inv; a1.y *= inv; a1.z *= inv; a1.w *= inv;
    qpl[(size_t)cg0*L_ + y*W_ + x] = a0;
    qpl[(size_t)cg1*L_ + y*W_ + x] = a1;
}

// ---------------- Kernel D: output projection via bf16 MFMA (64-o tiles) ----
// grid (64, 4, 2) = 512 blocks.
__global__ __launch_bounds__(256) void out_mfma(
    const float4* __restrict__ qt4, const unsigned* __restrict__ wb,
    const float* __restrict__ bo, float* __restrict__ out)
{
    const int b    = blockIdx.z;
    const int l0   = blockIdx.x * 64;
    const int o_t0 = blockIdx.y * 64;
    const unsigned* wbp = wb + 3*32768;
    const int tid  = threadIdx.x;
    const int lane = tid & 63, wave = tid >> 6;
    const int orow = lane & 15, kgrp = lane >> 4;

    __shared__ short Ws[64*WS_STR];    // 9.2 KB
    __shared__ short Xs[64*WS_STR];    // 9.2 KB

    f32x4 acc[4] = {};
    const int cq  = tid >> 6;
    const int lst = tid & 63;

    for (int ch = 0; ch < 4; ++ch) {
        const int c0 = ch*64;
        #pragma unroll
        for (int i = 0; i < 4; ++i) {
            int o  = i*16 + (tid>>4);
            int c4 = tid & 15;
            uint2 v = *reinterpret_cast<const uint2*>(wbp + (size_t)(o_t0 + o)*128 + (c0>>1) + c4*2);
            *reinterpret_cast<uint2*>(&Ws[o*WS_STR + c4*4]) = v;
        }
        #pragma unroll
        for (int i = 0; i < 4; ++i) {
            int c4i = i*4 + cq;
            float4 vv = qt4[(size_t)(b*64 + (c0>>2) + c4i)*L_ + l0 + lst];
            *reinterpret_cast<unsigned*>(&Xs[lst*WS_STR + c4i*4    ]) = pk2(vv.x, vv.y);
            *reinterpret_cast<unsigned*>(&Xs[lst*WS_STR + c4i*4 + 2]) = pk2(vv.z, vv.w);
        }
        __syncthreads();
        #pragma unroll
        for (int kk = 0; kk < 2; ++kk) {
            bf16x8 af, bfr[4];
            af = *reinterpret_cast<const bf16x8*>(&Ws[(wave*16 + orow)*WS_STR + kk*32 + kgrp*8]);
            #pragma unroll
            for (int fn = 0; fn < 4; ++fn)
                bfr[fn] = *reinterpret_cast<const bf16x8*>(&Xs[(fn*16 + orow)*WS_STR + kk*32 + kgrp*8]);
            #pragma unroll
            for (int fn = 0; fn < 4; ++fn)
                acc[fn] = __builtin_amdgcn_mfma_f32_16x16x32_bf16(af, bfr[fn], acc[fn], 0, 0, 0);
        }
        __syncthreads();
    }

    {
        const int o_base = o_t0 + wave*16 + kgrp*4;
        #pragma unroll
        for (int fn = 0; fn < 4; ++fn) {
            const int xl = fn*16 + orow;
            #pragma unroll
            for (int r = 0; r < 4; ++r)
                out[(size_t)(b*C_ + o_base + r)*L_ + l0 + xl] = acc[fn][r] + bo[o_base + r];
        }
    }
}

extern "C" void kernel_launch(void* const* d_in, const int* in_sizes, int n_in,
                              void* d_out, int out_size, void* d_ws, size_t ws_size,
                              hipStream_t stream) {
    const float* queries = (const float*)d_in[0];
    const float* keys    = (const float*)d_in[1];
    const float* values  = (const float*)d_in[2];
    const float* wq = (const float*)d_in[3];
    const float* bq = (const float*)d_in[4];
    const float* wk = (const float*)d_in[5];
    const float* bk = (const float*)d_in[6];
    const float* wv = (const float*)d_in[7];
    const float* bv = (const float*)d_in[8];
    const float* wo = (const float*)d_in[9];
    const float* bo = (const float*)d_in[10];
    float* out = (float*)d_out;

    float4* qt4 = (float4*)d_ws;                           // Q planar-c4, attn out in-place
    float4* kt4 = qt4 + (size_t)B_*HEADS_*CG_*L_;          // padded planar K
    float4* vt4 = kt4 + PADT4_;                            // padded planar V
    unsigned* wb = (unsigned*)(vt4 + PADT4_);              // bf16 packed weights

    const unsigned halo_blocks = (unsigned)((PADT4_ + 255)/256);
    prep<<<512 + halo_blocks, 256, 0, stream>>>(wq, wk, wv, wo, wb, kt4, vt4);
    qkv_mfma<<<dim3(64, 2, 6), 256, 0, stream>>>(queries, keys, values, wb, bq, bk, bv, qt4, kt4, vt4);
    local_attn<<<1024, 256, 0, stream>>>(qt4, kt4, vt4);
    out_mfma<<<dim3(64, 4, 2), 256, 0, stream>>>(qt4, wb, bo, out);
}

// Round 10
// 68.443 us; speedup vs baseline: 1.3211x; 1.0771x over previous
//
#include <hip/hip_runtime.h>
#include <hip/hip_bf16.h>
#include <math.h>

#define B_ 2
#define C_ 256
#define H_ 64
#define W_ 64
#define L_ 4096
#define HEADS_ 8
#define DH_ 32
#define CG_ 8
#define K_ 7
#define PAD_ 3
#define K2_ 49
#define PW_ 70
#define PPIX_ 4900
#define PADT_ ((size_t)B_*HEADS_*CG_*PPIX_)    // 627200 uint2 (bf16x4) per padded tensor
#define WS_STR 72                               // LDS row stride in bf16 (144B, 16B-aligned)

typedef short bf16x8 __attribute__((ext_vector_type(8)));
typedef float f32x4  __attribute__((ext_vector_type(4)));

__device__ inline unsigned short f2bf(float f) {
    union { float f; unsigned u; } uf; uf.f = f;
    unsigned r = uf.u + 0x7fffu + ((uf.u >> 16) & 1u);   // RNE
    return (unsigned short)(r >> 16);
}
__device__ inline unsigned pk2(float a, float b) {
    return (unsigned)f2bf(a) | ((unsigned)f2bf(b) << 16);
}

// ---------------- Kernel A: weight pack (bf16) + K/V halo zero --------------
__global__ __launch_bounds__(256) void prep(
    const float* __restrict__ wq, const float* __restrict__ wk,
    const float* __restrict__ wv, const float* __restrict__ wo,
    unsigned* __restrict__ wb, uint2* __restrict__ kt, uint2* __restrict__ vt)
{
    const int bidx = blockIdx.x;
    if (bidx < 512) {
        int idx = bidx*256 + threadIdx.x;   // 0..131071
        const float* src = (idx < 32768) ? wq : (idx < 65536) ? wk : (idx < 98304) ? wv : wo;
        int off = (idx & 32767) * 2;
        wb[idx] = pk2(src[off], src[off+1]);
    } else {
        int idx = (bidx - 512)*256 + threadIdx.x;
        if (idx >= (int)PADT_) return;
        int cell = idx % PPIX_;
        int px = cell % PW_, py = cell / PW_;
        if (px < PAD_ || px >= PW_-PAD_ || py < PAD_ || py >= PW_-PAD_) {
            uint2 z = make_uint2(0u, 0u);
            kt[idx] = z;
            vt[idx] = z;
        }
    }
}

// ---------------- Kernel B: QKV projection via bf16 MFMA (128-o tiles) ------
// Block: 128 o x 64 l (one image row). grid (64, 2, 6) = 768 blocks.
// Q -> planar-c4 f32; K/V -> padded planar bf16 (uint2 = 4 channels).
__global__ __launch_bounds__(256) void qkv_mfma(
    const float* __restrict__ q_in, const float* __restrict__ k_in, const float* __restrict__ v_in,
    const unsigned* __restrict__ wb,
    const float* __restrict__ bq, const float* __restrict__ bk, const float* __restrict__ bv,
    float4* __restrict__ qt4, uint2* __restrict__ kt2, uint2* __restrict__ vt2)
{
    const int z = blockIdx.z;
    const int which = z >> 1;      // 0=q,1=k,2=v
    const int b = z & 1;
    const float* X = (which==0) ? q_in : (which==1 ? k_in : v_in);
    const unsigned* wbp = wb + which*32768;
    const float* bias = (which==0) ? bq : (which==1 ? bk : bv);

    const int y    = blockIdx.x;
    const int l0   = y * 64;
    const int o_t0 = blockIdx.y * 128;
    const int tid  = threadIdx.x;
    const int lane = tid & 63, wave = tid >> 6;
    const int orow = lane & 15, kgrp = lane >> 4;

    __shared__ short Ws[128*WS_STR];   // weights [o][c-chunk]  (18.4 KB)
    __shared__ short Xs[64*WS_STR];    // input^T [l][c-chunk]  (9.2 KB)

    f32x4 acc[2][4] = {};
    const int cq  = tid >> 6;
    const int lst = tid & 63;

    for (int ch = 0; ch < 4; ++ch) {
        const int c0 = ch*64;
        #pragma unroll
        for (int i = 0; i < 8; ++i) {
            int o  = i*16 + (tid>>4);
            int c4 = tid & 15;
            uint2 v = *reinterpret_cast<const uint2*>(wbp + (size_t)(o_t0 + o)*128 + (c0>>1) + c4*2);
            *reinterpret_cast<uint2*>(&Ws[o*WS_STR + c4*4]) = v;
        }
        #pragma unroll
        for (int i = 0; i < 8; ++i) {
            int cc = cq*2 + i*8;
            float a  = X[(size_t)(b*C_ + c0 + cc    )*L_ + l0 + lst];
            float b2 = X[(size_t)(b*C_ + c0 + cc + 1)*L_ + l0 + lst];
            *reinterpret_cast<unsigned*>(&Xs[lst*WS_STR + cc]) = pk2(a, b2);
        }
        __syncthreads();
        #pragma unroll
        for (int kk = 0; kk < 2; ++kk) {
            bf16x8 af[2], bfr[4];
            #pragma unroll
            for (int fo = 0; fo < 2; ++fo)
                af[fo] = *reinterpret_cast<const bf16x8*>(&Ws[(wave*32 + fo*16 + orow)*WS_STR + kk*32 + kgrp*8]);
            #pragma unroll
            for (int fn = 0; fn < 4; ++fn)
                bfr[fn] = *reinterpret_cast<const bf16x8*>(&Xs[(fn*16 + orow)*WS_STR + kk*32 + kgrp*8]);
            #pragma unroll
            for (int fo = 0; fo < 2; ++fo)
                #pragma unroll
                for (int fn = 0; fn < 4; ++fn)
                    acc[fo][fn] = __builtin_amdgcn_mfma_f32_16x16x32_bf16(af[fo], bfr[fn], acc[fo][fn], 0, 0, 0);
        }
        __syncthreads();
    }

    #pragma unroll
    for (int fo = 0; fo < 2; ++fo) {
        const int og = o_t0 + wave*32 + fo*16 + kgrp*4;
        const float4 b4 = *reinterpret_cast<const float4*>(&bias[og]);
        const size_t p = (size_t)(b*64 + (og >> 2));   // plane index
        #pragma unroll
        for (int fn = 0; fn < 4; ++fn) {
            const int xl = fn*16 + orow;
            float4 r;
            r.x = acc[fo][fn][0] + b4.x;
            r.y = acc[fo][fn][1] + b4.y;
            r.z = acc[fo][fn][2] + b4.z;
            r.w = acc[fo][fn][3] + b4.w;
            if (which == 0) {
                qt4[p*L_ + l0 + xl] = r;
            } else {
                uint2* dst = (which==1) ? kt2 : vt2;
                dst[p*PPIX_ + (size_t)(y+PAD_)*PW_ + (xl+PAD_)] =
                    make_uint2(pk2(r.x, r.y), pk2(r.z, r.w));
            }
        }
    }
}

// ---------------- Kernel C: 7x7 local attention, bf16 K/V, 1-row blocks -----
// Block = (plane=b*8+h, image row y), 256 threads (4 waves), grid 1024.
// K/V taps are uint2 (4 bf16 channels) -> half the L1/L2/HBM bytes of f32.
__global__ __launch_bounds__(256) void local_attn(
    float4* __restrict__ qt4, const uint2* __restrict__ kt2, const uint2* __restrict__ vt2)
{
    const int tid = threadIdx.x;
    const int w = tid >> 6, x = tid & 63;
    const int bid = blockIdx.x;
    const int plane = bid & 15;      // plane -> XCD plane%8: K/V L2-resident per XCD
    const int y = bid >> 4;          // 0..63

    const uint2* kb = kt2 + (size_t)plane*CG_*PPIX_;
    const uint2* vb = vt2 + (size_t)plane*CG_*PPIX_;
    float4* qpl = qt4 + (size_t)plane*CG_*L_;

    __shared__ float S[K2_][64];     // 12.25 KB

    // ---- QK: my window rows r = w and w+4 ----
    float lg[2][K_] = {};
    #pragma unroll
    for (int cg=0; cg<CG_; ++cg) {
        const float4 q = qpl[(size_t)cg*L_ + y*W_ + x];
        #pragma unroll
        for (int rr=0; rr<2; ++rr) {
            const int r = w + rr*4;
            if (r > 6) continue;                  // only w=3,rr=1 skips (uniform)
            const uint2* row = kb + (size_t)cg*PPIX_ + (size_t)(y + r)*PW_ + x;
            #pragma unroll
            for (int kx=0; kx<K_; ++kx) {
                uint2 kk = row[kx];
                float k0 = __uint_as_float(kk.x << 16);
                float k1 = __uint_as_float(kk.x & 0xffff0000u);
                float k2 = __uint_as_float(kk.y << 16);
                float k3 = __uint_as_float(kk.y & 0xffff0000u);
                lg[rr][kx] = fmaf(q.x,k0, fmaf(q.y,k1, fmaf(q.z,k2, fmaf(q.w,k3, lg[rr][kx]))));
            }
        }
    }
    #pragma unroll
    for (int rr=0; rr<2; ++rr) {
        const int r = w + rr*4;
        if (r <= 6) {
            #pragma unroll
            for (int kx=0; kx<K_; ++kx) S[r*K_+kx][x] = lg[rr][kx];
        }
    }
    __syncthreads();

    const float scale = 0.0625f; // 1/sqrt(256)

    // ---- denominator: scalar scan over S (no max needed: |logit*scale| small) --
    float sum = 0.f;
    #pragma unroll
    for (int i=0;i<K2_;++i) sum += __expf(S[i][x]*scale);
    const float inv = 1.0f/sum;

    // ---- PV: my channel-groups {2w, 2w+1}; exp recomputed per tap ----
    const int cg0 = w*2, cg1 = w*2 + 1;
    float4 a0 = make_float4(0.f,0.f,0.f,0.f);
    float4 a1 = make_float4(0.f,0.f,0.f,0.f);
    #pragma unroll
    for (int r=0; r<K_; ++r) {
        const uint2* row0 = vb + (size_t)cg0*PPIX_ + (size_t)(y + r)*PW_ + x;
        const uint2* row1 = vb + (size_t)cg1*PPIX_ + (size_t)(y + r)*PW_ + x;
        #pragma unroll
        for (int kx=0; kx<K_; ++kx) {
            const float p = __expf(S[r*K_+kx][x]*scale);
            uint2 u0 = row0[kx];
            uint2 u1 = row1[kx];
            float v00 = __uint_as_float(u0.x << 16);
            float v01 = __uint_as_float(u0.x & 0xffff0000u);
            float v02 = __uint_as_float(u0.y << 16);
            float v03 = __uint_as_float(u0.y & 0xffff0000u);
            float v10 = __uint_as_float(u1.x << 16);
            float v11 = __uint_as_float(u1.x & 0xffff0000u);
            float v12 = __uint_as_float(u1.y << 16);
            float v13 = __uint_as_float(u1.y & 0xffff0000u);
            a0.x = fmaf(p, v00, a0.x); a0.y = fmaf(p, v01, a0.y);
            a0.z = fmaf(p, v02, a0.z); a0.w = fmaf(p, v03, a0.w);
            a1.x = fmaf(p, v10, a1.x); a1.y = fmaf(p, v11, a1.y);
            a1.z = fmaf(p, v12, a1.z); a1.w = fmaf(p, v13, a1.w);
        }
    }
    a0.x *= inv; a0.y *= inv; a0.z *= inv; a0.w *= inv;
    a1.x *= inv; a1.y *= inv; a1.z *= inv; a1.w *= inv;
    qpl[(size_t)cg0*L_ + y*W_ + x] = a0;
    qpl[(size_t)cg1*L_ + y*W_ + x] = a1;
}

// ---------------- Kernel D: output projection via bf16 MFMA (64-o tiles) ----
// grid (64, 4, 2) = 512 blocks.
__global__ __launch_bounds__(256) void out_mfma(
    const float4* __restrict__ qt4, const unsigned* __restrict__ wb,
    const float* __restrict__ bo, float* __restrict__ out)
{
    const int b    = blockIdx.z;
    const int l0   = blockIdx.x * 64;
    const int o_t0 = blockIdx.y * 64;
    const unsigned* wbp = wb + 3*32768;
    const int tid  = threadIdx.x;
    const int lane = tid & 63, wave = tid >> 6;
    const int orow = lane & 15, kgrp = lane >> 4;

    __shared__ short Ws[64*WS_STR];    // 9.2 KB
    __shared__ short Xs[64*WS_STR];    // 9.2 KB

    f32x4 acc[4] = {};
    const int cq  = tid >> 6;
    const int lst = tid & 63;

    for (int ch = 0; ch < 4; ++ch) {
        const int c0 = ch*64;
        #pragma unroll
        for (int i = 0; i < 4; ++i) {
            int o  = i*16 + (tid>>4);
            int c4 = tid & 15;
            uint2 v = *reinterpret_cast<const uint2*>(wbp + (size_t)(o_t0 + o)*128 + (c0>>1) + c4*2);
            *reinterpret_cast<uint2*>(&Ws[o*WS_STR + c4*4]) = v;
        }
        #pragma unroll
        for (int i = 0; i < 4; ++i) {
            int c4i = i*4 + cq;
            float4 vv = qt4[(size_t)(b*64 + (c0>>2) + c4i)*L_ + l0 + lst];
            *reinterpret_cast<unsigned*>(&Xs[lst*WS_STR + c4i*4    ]) = pk2(vv.x, vv.y);
            *reinterpret_cast<unsigned*>(&Xs[lst*WS_STR + c4i*4 + 2]) = pk2(vv.z, vv.w);
        }
        __syncthreads();
        #pragma unroll
        for (int kk = 0; kk < 2; ++kk) {
            bf16x8 af, bfr[4];
            af = *reinterpret_cast<const bf16x8*>(&Ws[(wave*16 + orow)*WS_STR + kk*32 + kgrp*8]);
            #pragma unroll
            for (int fn = 0; fn < 4; ++fn)
                bfr[fn] = *reinterpret_cast<const bf16x8*>(&Xs[(fn*16 + orow)*WS_STR + kk*32 + kgrp*8]);
            #pragma unroll
            for (int fn = 0; fn < 4; ++fn)
                acc[fn] = __builtin_amdgcn_mfma_f32_16x16x32_bf16(af, bfr[fn], acc[fn], 0, 0, 0);
        }
        __syncthreads();
    }

    {
        const int o_base = o_t0 + wave*16 + kgrp*4;
        #pragma unroll
        for (int fn = 0; fn < 4; ++fn) {
            const int xl = fn*16 + orow;
            #pragma unroll
            for (int r = 0; r < 4; ++r)
                out[(size_t)(b*C_ + o_base + r)*L_ + l0 + xl] = acc[fn][r] + bo[o_base + r];
        }
    }
}

extern "C" void kernel_launch(void* const* d_in, const int* in_sizes, int n_in,
                              void* d_out, int out_size, void* d_ws, size_t ws_size,
                              hipStream_t stream) {
    const float* queries = (const float*)d_in[0];
    const float* keys    = (const float*)d_in[1];
    const float* values  = (const float*)d_in[2];
    const float* wq = (const float*)d_in[3];
    const float* bq = (const float*)d_in[4];
    const float* wk = (const float*)d_in[5];
    const float* bk = (const float*)d_in[6];
    const float* wv = (const float*)d_in[7];
    const float* bv = (const float*)d_in[8];
    const float* wo = (const float*)d_in[9];
    const float* bo = (const float*)d_in[10];
    float* out = (float*)d_out;

    float4* qt4 = (float4*)d_ws;                           // Q planar-c4 f32, attn out in-place
    uint2*  kt2 = (uint2*)(qt4 + (size_t)B_*HEADS_*CG_*L_);// padded planar K (bf16 x4)
    uint2*  vt2 = kt2 + PADT_;                             // padded planar V (bf16 x4)
    unsigned* wb = (unsigned*)(vt2 + PADT_);               // bf16 packed weights

    const unsigned halo_blocks = (unsigned)((PADT_ + 255)/256);
    prep<<<512 + halo_blocks, 256, 0, stream>>>(wq, wk, wv, wo, wb, kt2, vt2);
    qkv_mfma<<<dim3(64, 2, 6), 256, 0, stream>>>(queries, keys, values, wb, bq, bk, bv, qt4, kt2, vt2);
    local_attn<<<1024, 256, 0, stream>>>(qt4, kt2, vt2);
    out_mfma<<<dim3(64, 4, 2), 256, 0, stream>>>(qt4, wb, bo, out);
}

// Round 11
// 63.878 us; speedup vs baseline: 1.4155x; 1.0715x over previous
//
#include <hip/hip_runtime.h>
#include <hip/hip_bf16.h>
#include <math.h>

#define B_ 2
#define C_ 256
#define H_ 64
#define W_ 64
#define L_ 4096
#define HEADS_ 8
#define DH_ 32
#define CG_ 8
#define K_ 7
#define PAD_ 3
#define K2_ 49
#define PW_ 70
#define PPIX_ 4900
#define PADT_ ((size_t)B_*HEADS_*CG_*PPIX_)    // 627200 uint2 (bf16x4) per padded tensor
#define WS_STR 72                               // LDS row stride in bf16 (144B, 16B-aligned)

typedef short bf16x8 __attribute__((ext_vector_type(8)));
typedef float f32x4  __attribute__((ext_vector_type(4)));

__device__ inline unsigned short f2bf(float f) {
    union { float f; unsigned u; } uf; uf.f = f;
    unsigned r = uf.u + 0x7fffu + ((uf.u >> 16) & 1u);   // RNE
    return (unsigned short)(r >> 16);
}
__device__ inline unsigned pk2(float a, float b) {
    return (unsigned)f2bf(a) | ((unsigned)f2bf(b) << 16);
}

// ---------------- Kernel A: weight pack (bf16) only -------------------------
__global__ __launch_bounds__(256) void prep(
    const float* __restrict__ wq, const float* __restrict__ wk,
    const float* __restrict__ wv, const float* __restrict__ wo,
    unsigned* __restrict__ wb)
{
    int idx = blockIdx.x*256 + threadIdx.x;   // 0..131071
    const float* src = (idx < 32768) ? wq : (idx < 65536) ? wk : (idx < 98304) ? wv : wo;
    int off = (idx & 32767) * 2;
    wb[idx] = pk2(src[off], src[off+1]);
}

// ---------------- Kernel B: QKV projection via bf16 MFMA + halo-zero slice --
// z = 0..5: GEMM (which = z>>1, b = z&1), 128 o x 64 l per block.
// z = 6:    K/V halo zeroing (write-disjoint from GEMM interior writes).
__global__ __launch_bounds__(256) void qkv_mfma(
    const float* __restrict__ q_in, const float* __restrict__ k_in, const float* __restrict__ v_in,
    const unsigned* __restrict__ wb,
    const float* __restrict__ bq, const float* __restrict__ bk, const float* __restrict__ bv,
    float4* __restrict__ qt4, uint2* __restrict__ kt2, uint2* __restrict__ vt2)
{
    const int z = blockIdx.z;
    const int tid = threadIdx.x;

    if (z == 6) {
        // halo zeroing: 128 blocks grid-stride over both padded tensors
        const int flat = blockIdx.x + 64*blockIdx.y;   // 0..127
        const uint2 zz = make_uint2(0u, 0u);
        for (size_t idx = (size_t)flat*256 + tid; idx < PADT_; idx += 128*256) {
            int cell = (int)(idx % PPIX_);
            int px = cell % PW_, py = cell / PW_;
            if (px < PAD_ || px >= PW_-PAD_ || py < PAD_ || py >= PW_-PAD_) {
                kt2[idx] = zz;
                vt2[idx] = zz;
            }
        }
        return;
    }

    const int which = z >> 1;      // 0=q,1=k,2=v
    const int b = z & 1;
    const float* X = (which==0) ? q_in : (which==1 ? k_in : v_in);
    const unsigned* wbp = wb + which*32768;
    const float* bias = (which==0) ? bq : (which==1 ? bk : bv);

    const int y    = blockIdx.x;
    const int l0   = y * 64;
    const int o_t0 = blockIdx.y * 128;
    const int lane = tid & 63, wave = tid >> 6;
    const int orow = lane & 15, kgrp = lane >> 4;

    __shared__ short Ws[128*WS_STR];   // weights [o][c-chunk]  (18.4 KB)
    __shared__ short Xs[64*WS_STR];    // input^T [l][c-chunk]  (9.2 KB)

    f32x4 acc[2][4] = {};

    for (int ch = 0; ch < 4; ++ch) {
        const int c0 = ch*64;
        #pragma unroll
        for (int i = 0; i < 8; ++i) {
            int o  = i*16 + (tid>>4);
            int c4 = tid & 15;
            uint2 v = *reinterpret_cast<const uint2*>(wbp + (size_t)(o_t0 + o)*128 + (c0>>1) + c4*2);
            *reinterpret_cast<uint2*>(&Ws[o*WS_STR + c4*4]) = v;
        }
        // Xs staging: float4 along l (4 VMEM instrs/chunk), b16 transpose writes
        #pragma unroll
        for (int i = 0; i < 4; ++i) {
            int c_loc = (tid>>4) + i*16;        // 0..63
            int l4    = (tid&15)*4;             // 0,4,...,60
            float4 xv = *reinterpret_cast<const float4*>(&X[(size_t)(b*C_ + c0 + c_loc)*L_ + l0 + l4]);
            Xs[(l4+0)*WS_STR + c_loc] = (short)f2bf(xv.x);
            Xs[(l4+1)*WS_STR + c_loc] = (short)f2bf(xv.y);
            Xs[(l4+2)*WS_STR + c_loc] = (short)f2bf(xv.z);
            Xs[(l4+3)*WS_STR + c_loc] = (short)f2bf(xv.w);
        }
        __syncthreads();
        #pragma unroll
        for (int kk = 0; kk < 2; ++kk) {
            bf16x8 af[2], bfr[4];
            #pragma unroll
            for (int fo = 0; fo < 2; ++fo)
                af[fo] = *reinterpret_cast<const bf16x8*>(&Ws[(wave*32 + fo*16 + orow)*WS_STR + kk*32 + kgrp*8]);
            #pragma unroll
            for (int fn = 0; fn < 4; ++fn)
                bfr[fn] = *reinterpret_cast<const bf16x8*>(&Xs[(fn*16 + orow)*WS_STR + kk*32 + kgrp*8]);
            #pragma unroll
            for (int fo = 0; fo < 2; ++fo)
                #pragma unroll
                for (int fn = 0; fn < 4; ++fn)
                    acc[fo][fn] = __builtin_amdgcn_mfma_f32_16x16x32_bf16(af[fo], bfr[fn], acc[fo][fn], 0, 0, 0);
        }
        __syncthreads();
    }

    #pragma unroll
    for (int fo = 0; fo < 2; ++fo) {
        const int og = o_t0 + wave*32 + fo*16 + kgrp*4;
        const float4 b4 = *reinterpret_cast<const float4*>(&bias[og]);
        const size_t p = (size_t)(b*64 + (og >> 2));   // plane index
        #pragma unroll
        for (int fn = 0; fn < 4; ++fn) {
            const int xl = fn*16 + orow;
            float4 r;
            r.x = acc[fo][fn][0] + b4.x;
            r.y = acc[fo][fn][1] + b4.y;
            r.z = acc[fo][fn][2] + b4.z;
            r.w = acc[fo][fn][3] + b4.w;
            if (which == 0) {
                qt4[p*L_ + l0 + xl] = r;
            } else {
                uint2* dst = (which==1) ? kt2 : vt2;
                dst[p*PPIX_ + (size_t)(y+PAD_)*PW_ + (xl+PAD_)] =
                    make_uint2(pk2(r.x, r.y), pk2(r.z, r.w));
            }
        }
    }
}

// ---------------- Kernel C: 7x7 local attention, bf16 K/V, P-in-LDS ---------
// Block = (plane=b*8+h, image row y), 256 threads (4 waves), grid 1024.
// QK: wave w -> window rows {w, w+4}; stores P = exp(logit*scale) directly
//     (no max-sub: |logit*scale| is small; identical math). 14 exp/thread.
// Sum: scan P from LDS (no exp). PV: wave w -> cgs {2w,2w+1}, P from LDS.
__global__ __launch_bounds__(256) void local_attn(
    float4* __restrict__ qt4, const uint2* __restrict__ kt2, const uint2* __restrict__ vt2)
{
    const int tid = threadIdx.x;
    const int w = tid >> 6, x = tid & 63;
    const int bid = blockIdx.x;
    const int plane = bid & 15;      // plane -> XCD plane%8: K/V L2-resident per XCD
    const int y = bid >> 4;          // 0..63

    const uint2* kb = kt2 + (size_t)plane*CG_*PPIX_;
    const uint2* vb = vt2 + (size_t)plane*CG_*PPIX_;
    float4* qpl = qt4 + (size_t)plane*CG_*L_;

    __shared__ float S[K2_][64];     // holds P = exp(logit*scale); 12.25 KB

    const float scale = 0.0625f; // 1/sqrt(256)

    // ---- QK: my window rows r = w and w+4 ----
    float lg[2][K_] = {};
    #pragma unroll
    for (int cg=0; cg<CG_; ++cg) {
        const float4 q = qpl[(size_t)cg*L_ + y*W_ + x];
        #pragma unroll
        for (int rr=0; rr<2; ++rr) {
            const int r = w + rr*4;
            if (r > 6) continue;                  // only w=3,rr=1 skips (uniform)
            const uint2* row = kb + (size_t)cg*PPIX_ + (size_t)(y + r)*PW_ + x;
            #pragma unroll
            for (int kx=0; kx<K_; ++kx) {
                uint2 kk = row[kx];
                float k0 = __uint_as_float(kk.x << 16);
                float k1 = __uint_as_float(kk.x & 0xffff0000u);
                float k2 = __uint_as_float(kk.y << 16);
                float k3 = __uint_as_float(kk.y & 0xffff0000u);
                lg[rr][kx] = fmaf(q.x,k0, fmaf(q.y,k1, fmaf(q.z,k2, fmaf(q.w,k3, lg[rr][kx]))));
            }
        }
    }
    #pragma unroll
    for (int rr=0; rr<2; ++rr) {
        const int r = w + rr*4;
        if (r <= 6) {
            #pragma unroll
            for (int kx=0; kx<K_; ++kx) S[r*K_+kx][x] = __expf(lg[rr][kx]*scale);
        }
    }
    __syncthreads();

    // ---- denominator: plain sum of P from LDS (no exp) ----
    float sum = 0.f;
    #pragma unroll
    for (int i=0;i<K2_;++i) sum += S[i][x];
    const float inv = 1.0f/sum;

    // ---- PV: my channel-groups {2w, 2w+1}; P read from LDS ----
    const int cg0 = w*2, cg1 = w*2 + 1;
    float4 a0 = make_float4(0.f,0.f,0.f,0.f);
    float4 a1 = make_float4(0.f,0.f,0.f,0.f);
    #pragma unroll
    for (int r=0; r<K_; ++r) {
        const uint2* row0 = vb + (size_t)cg0*PPIX_ + (size_t)(y + r)*PW_ + x;
        const uint2* row1 = vb + (size_t)cg1*PPIX_ + (size_t)(y + r)*PW_ + x;
        #pragma unroll
        for (int kx=0; kx<K_; ++kx) {
            const float p = S[r*K_+kx][x];
            uint2 u0 = row0[kx];
            uint2 u1 = row1[kx];
            float v00 = __uint_as_float(u0.x << 16);
            float v01 = __uint_as_float(u0.x & 0xffff0000u);
            float v02 = __uint_as_float(u0.y << 16);
            float v03 = __uint_as_float(u0.y & 0xffff0000u);
            float v10 = __uint_as_float(u1.x << 16);
            float v11 = __uint_as_float(u1.x & 0xffff0000u);
            float v12 = __uint_as_float(u1.y << 16);
            float v13 = __uint_as_float(u1.y & 0xffff0000u);
            a0.x = fmaf(p, v00, a0.x); a0.y = fmaf(p, v01, a0.y);
            a0.z = fmaf(p, v02, a0.z); a0.w = fmaf(p, v03, a0.w);
            a1.x = fmaf(p, v10, a1.x); a1.y = fmaf(p, v11, a1.y);
            a1.z = fmaf(p, v12, a1.z); a1.w = fmaf(p, v13, a1.w);
        }
    }
    a0.x *= inv; a0.y *= inv; a0.z *= inv; a0.w *= inv;
    a1.x *= inv; a1.y *= inv; a1.z *= inv; a1.w *= inv;
    qpl[(size_t)cg0*L_ + y*W_ + x] = a0;
    qpl[(size_t)cg1*L_ + y*W_ + x] = a1;
}

// ---------------- Kernel D: output projection via bf16 MFMA (64-o tiles) ----
// grid (64, 4, 2) = 512 blocks.
__global__ __launch_bounds__(256) void out_mfma(
    const float4* __restrict__ qt4, const unsigned* __restrict__ wb,
    const float* __restrict__ bo, float* __restrict__ out)
{
    const int b    = blockIdx.z;
    const int l0   = blockIdx.x * 64;
    const int o_t0 = blockIdx.y * 64;
    const unsigned* wbp = wb + 3*32768;
    const int tid  = threadIdx.x;
    const int lane = tid & 63, wave = tid >> 6;
    const int orow = lane & 15, kgrp = lane >> 4;

    __shared__ short Ws[64*WS_STR];    // 9.2 KB
    __shared__ short Xs[64*WS_STR];    // 9.2 KB

    f32x4 acc[4] = {};
    const int cq  = tid >> 6;
    const int lst = tid & 63;

    for (int ch = 0; ch < 4; ++ch) {
        const int c0 = ch*64;
        #pragma unroll
        for (int i = 0; i < 4; ++i) {
            int o  = i*16 + (tid>>4);
            int c4 = tid & 15;
            uint2 v = *reinterpret_cast<const uint2*>(wbp + (size_t)(o_t0 + o)*128 + (c0>>1) + c4*2);
            *reinterpret_cast<uint2*>(&Ws[o*WS_STR + c4*4]) = v;
        }
        #pragma unroll
        for (int i = 0; i < 4; ++i) {
            int c4i = i*4 + cq;
            float4 vv = qt4[(size_t)(b*64 + (c0>>2) + c4i)*L_ + l0 + lst];
            *reinterpret_cast<unsigned*>(&Xs[lst*WS_STR + c4i*4    ]) = pk2(vv.x, vv.y);
            *reinterpret_cast<unsigned*>(&Xs[lst*WS_STR + c4i*4 + 2]) = pk2(vv.z, vv.w);
        }
        __syncthreads();
        #pragma unroll
        for (int kk = 0; kk < 2; ++kk) {
            bf16x8 af, bfr[4];
            af = *reinterpret_cast<const bf16x8*>(&Ws[(wave*16 + orow)*WS_STR + kk*32 + kgrp*8]);
            #pragma unroll
            for (int fn = 0; fn < 4; ++fn)
                bfr[fn] = *reinterpret_cast<const bf16x8*>(&Xs[(fn*16 + orow)*WS_STR + kk*32 + kgrp*8]);
            #pragma unroll
            for (int fn = 0; fn < 4; ++fn)
                acc[fn] = __builtin_amdgcn_mfma_f32_16x16x32_bf16(af, bfr[fn], acc[fn], 0, 0, 0);
        }
        __syncthreads();
    }

    {
        const int o_base = o_t0 + wave*16 + kgrp*4;
        #pragma unroll
        for (int fn = 0; fn < 4; ++fn) {
            const int xl = fn*16 + orow;
            #pragma unroll
            for (int r = 0; r < 4; ++r)
                out[(size_t)(b*C_ + o_base + r)*L_ + l0 + xl] = acc[fn][r] + bo[o_base + r];
        }
    }
}

extern "C" void kernel_launch(void* const* d_in, const int* in_sizes, int n_in,
                              void* d_out, int out_size, void* d_ws, size_t ws_size,
                              hipStream_t stream) {
    const float* queries = (const float*)d_in[0];
    const float* keys    = (const float*)d_in[1];
    const float* values  = (const float*)d_in[2];
    const float* wq = (const float*)d_in[3];
    const float* bq = (const float*)d_in[4];
    const float* wk = (const float*)d_in[5];
    const float* bk = (const float*)d_in[6];
    const float* wv = (const float*)d_in[7];
    const float* bv = (const float*)d_in[8];
    const float* wo = (const float*)d_in[9];
    const float* bo = (const float*)d_in[10];
    float* out = (float*)d_out;

    float4* qt4 = (float4*)d_ws;                           // Q planar-c4 f32, attn out in-place
    uint2*  kt2 = (uint2*)(qt4 + (size_t)B_*HEADS_*CG_*L_);// padded planar K (bf16 x4)
    uint2*  vt2 = kt2 + PADT_;                             // padded planar V (bf16 x4)
    unsigned* wb = (unsigned*)(vt2 + PADT_);               // bf16 packed weights

    prep<<<512, 256, 0, stream>>>(wq, wk, wv, wo, wb);
    qkv_mfma<<<dim3(64, 2, 7), 256, 0, stream>>>(queries, keys, values, wb, bq, bk, bv, qt4, kt2, vt2);
    local_attn<<<1024, 256, 0, stream>>>(qt4, kt2, vt2);
    out_mfma<<<dim3(64, 4, 2), 256, 0, stream>>>(qt4, wb, bo, out);
}

// Round 12
// 53.262 us; speedup vs baseline: 1.6977x; 1.1993x over previous
//
#include <hip/hip_runtime.h>
#include <hip/hip_bf16.h>
#include <math.h>

#define B_ 2
#define C_ 256
#define H_ 64
#define W_ 64
#define L_ 4096
#define HEADS_ 8
#define DH_ 32
#define CG_ 8
#define K_ 7
#define PAD_ 3
#define K2_ 49
#define PW_ 70
#define PPIX_ 4900
#define PADT_ ((size_t)B_*HEADS_*CG_*PPIX_)    // 627200 uint2 (bf16x4) per padded tensor
#define WS_STR 72                               // LDS row stride in bf16 (144B, 16B-aligned)

typedef short bf16x8 __attribute__((ext_vector_type(8)));
typedef float f32x4  __attribute__((ext_vector_type(4)));

__device__ inline unsigned short f2bf(float f) {
    union { float f; unsigned u; } uf; uf.f = f;
    unsigned r = uf.u + 0x7fffu + ((uf.u >> 16) & 1u);   // RNE
    return (unsigned short)(r >> 16);
}
__device__ inline unsigned pk2(float a, float b) {
    return (unsigned)f2bf(a) | ((unsigned)f2bf(b) << 16);
}

// ---------------- Kernel A: weight pack (bf16) only -------------------------
__global__ __launch_bounds__(256) void prep(
    const float* __restrict__ wq, const float* __restrict__ wk,
    const float* __restrict__ wv, const float* __restrict__ wo,
    unsigned* __restrict__ wb)
{
    int idx = blockIdx.x*256 + threadIdx.x;   // 0..131071
    const float* src = (idx < 32768) ? wq : (idx < 65536) ? wk : (idx < 98304) ? wv : wo;
    int off = (idx & 32767) * 2;
    wb[idx] = pk2(src[off], src[off+1]);
}

// ---------------- Kernel B: QKV projection via bf16 MFMA + halo-zero slice --
// z = 0..5: GEMM (which = z>>1, b = z&1), 128 o x 64 l per block.
// z = 6:    K/V halo zeroing (write-disjoint from GEMM interior writes).
// ALL outputs bf16-packed (uint2 = 4 channels): Q planar [plane][l],
// K/V padded planar [plane][py][px].
__global__ __launch_bounds__(256) void qkv_mfma(
    const float* __restrict__ q_in, const float* __restrict__ k_in, const float* __restrict__ v_in,
    const unsigned* __restrict__ wb,
    const float* __restrict__ bq, const float* __restrict__ bk, const float* __restrict__ bv,
    uint2* __restrict__ qt2, uint2* __restrict__ kt2, uint2* __restrict__ vt2)
{
    const int z = blockIdx.z;
    const int tid = threadIdx.x;

    if (z == 6) {
        const int flat = blockIdx.x + 64*blockIdx.y;   // 0..127
        const uint2 zz = make_uint2(0u, 0u);
        for (size_t idx = (size_t)flat*256 + tid; idx < PADT_; idx += 128*256) {
            int cell = (int)(idx % PPIX_);
            int px = cell % PW_, py = cell / PW_;
            if (px < PAD_ || px >= PW_-PAD_ || py < PAD_ || py >= PW_-PAD_) {
                kt2[idx] = zz;
                vt2[idx] = zz;
            }
        }
        return;
    }

    const int which = z >> 1;      // 0=q,1=k,2=v
    const int b = z & 1;
    const float* X = (which==0) ? q_in : (which==1 ? k_in : v_in);
    const unsigned* wbp = wb + which*32768;
    const float* bias = (which==0) ? bq : (which==1 ? bk : bv);

    const int y    = blockIdx.x;
    const int l0   = y * 64;
    const int o_t0 = blockIdx.y * 128;
    const int lane = tid & 63, wave = tid >> 6;
    const int orow = lane & 15, kgrp = lane >> 4;

    __shared__ short Ws[128*WS_STR];   // weights [o][c-chunk]  (18.4 KB)
    __shared__ short Xs[64*WS_STR];    // input^T [l][c-chunk]  (9.2 KB)

    f32x4 acc[2][4] = {};

    for (int ch = 0; ch < 4; ++ch) {
        const int c0 = ch*64;
        #pragma unroll
        for (int i = 0; i < 8; ++i) {
            int o  = i*16 + (tid>>4);
            int c4 = tid & 15;
            uint2 v = *reinterpret_cast<const uint2*>(wbp + (size_t)(o_t0 + o)*128 + (c0>>1) + c4*2);
            *reinterpret_cast<uint2*>(&Ws[o*WS_STR + c4*4]) = v;
        }
        // Xs staging: float4 along l (4 VMEM instrs/chunk), b16 transpose writes
        #pragma unroll
        for (int i = 0; i < 4; ++i) {
            int c_loc = (tid>>4) + i*16;        // 0..63
            int l4    = (tid&15)*4;             // 0,4,...,60
            float4 xv = *reinterpret_cast<const float4*>(&X[(size_t)(b*C_ + c0 + c_loc)*L_ + l0 + l4]);
            Xs[(l4+0)*WS_STR + c_loc] = (short)f2bf(xv.x);
            Xs[(l4+1)*WS_STR + c_loc] = (short)f2bf(xv.y);
            Xs[(l4+2)*WS_STR + c_loc] = (short)f2bf(xv.z);
            Xs[(l4+3)*WS_STR + c_loc] = (short)f2bf(xv.w);
        }
        __syncthreads();
        #pragma unroll
        for (int kk = 0; kk < 2; ++kk) {
            bf16x8 af[2], bfr[4];
            #pragma unroll
            for (int fo = 0; fo < 2; ++fo)
                af[fo] = *reinterpret_cast<const bf16x8*>(&Ws[(wave*32 + fo*16 + orow)*WS_STR + kk*32 + kgrp*8]);
            #pragma unroll
            for (int fn = 0; fn < 4; ++fn)
                bfr[fn] = *reinterpret_cast<const bf16x8*>(&Xs[(fn*16 + orow)*WS_STR + kk*32 + kgrp*8]);
            #pragma unroll
            for (int fo = 0; fo < 2; ++fo)
                #pragma unroll
                for (int fn = 0; fn < 4; ++fn)
                    acc[fo][fn] = __builtin_amdgcn_mfma_f32_16x16x32_bf16(af[fo], bfr[fn], acc[fo][fn], 0, 0, 0);
        }
        __syncthreads();
    }

    #pragma unroll
    for (int fo = 0; fo < 2; ++fo) {
        const int og = o_t0 + wave*32 + fo*16 + kgrp*4;
        const float4 b4 = *reinterpret_cast<const float4*>(&bias[og]);
        const size_t p = (size_t)(b*64 + (og >> 2));   // plane index
        #pragma unroll
        for (int fn = 0; fn < 4; ++fn) {
            const int xl = fn*16 + orow;
            uint2 r = make_uint2(pk2(acc[fo][fn][0] + b4.x, acc[fo][fn][1] + b4.y),
                                 pk2(acc[fo][fn][2] + b4.z, acc[fo][fn][3] + b4.w));
            if (which == 0) {
                qt2[p*L_ + l0 + xl] = r;
            } else {
                uint2* dst = (which==1) ? kt2 : vt2;
                dst[p*PPIX_ + (size_t)(y+PAD_)*PW_ + (xl+PAD_)] = r;
            }
        }
    }
}

// ---------------- Kernel C: 7x7 local attention, all-bf16, P-in-LDS ---------
// Block = (plane=b*8+h, image row y), 256 threads (4 waves), grid 1024.
__global__ __launch_bounds__(256) void local_attn(
    uint2* __restrict__ qt2, const uint2* __restrict__ kt2, const uint2* __restrict__ vt2)
{
    const int tid = threadIdx.x;
    const int w = tid >> 6, x = tid & 63;
    const int bid = blockIdx.x;
    const int plane = bid & 15;      // plane -> XCD plane%8: K/V L2-resident per XCD
    const int y = bid >> 4;          // 0..63

    const uint2* kb = kt2 + (size_t)plane*CG_*PPIX_;
    const uint2* vb = vt2 + (size_t)plane*CG_*PPIX_;
    uint2* qpl = qt2 + (size_t)plane*CG_*L_;

    __shared__ float S[K2_][64];     // holds P = exp(logit*scale); 12.25 KB

    const float scale = 0.0625f; // 1/sqrt(256)

    // ---- QK: my window rows r = w and w+4 ----
    float lg[2][K_] = {};
    #pragma unroll
    for (int cg=0; cg<CG_; ++cg) {
        uint2 qu = qpl[(size_t)cg*L_ + y*W_ + x];
        const float qx = __uint_as_float(qu.x << 16);
        const float qy = __uint_as_float(qu.x & 0xffff0000u);
        const float qz = __uint_as_float(qu.y << 16);
        const float qw = __uint_as_float(qu.y & 0xffff0000u);
        #pragma unroll
        for (int rr=0; rr<2; ++rr) {
            const int r = w + rr*4;
            if (r > 6) continue;                  // only w=3,rr=1 skips (uniform)
            const uint2* row = kb + (size_t)cg*PPIX_ + (size_t)(y + r)*PW_ + x;
            #pragma unroll
            for (int kx=0; kx<K_; ++kx) {
                uint2 kk = row[kx];
                float k0 = __uint_as_float(kk.x << 16);
                float k1 = __uint_as_float(kk.x & 0xffff0000u);
                float k2 = __uint_as_float(kk.y << 16);
                float k3 = __uint_as_float(kk.y & 0xffff0000u);
                lg[rr][kx] = fmaf(qx,k0, fmaf(qy,k1, fmaf(qz,k2, fmaf(qw,k3, lg[rr][kx]))));
            }
        }
    }
    #pragma unroll
    for (int rr=0; rr<2; ++rr) {
        const int r = w + rr*4;
        if (r <= 6) {
            #pragma unroll
            for (int kx=0; kx<K_; ++kx) S[r*K_+kx][x] = __expf(lg[rr][kx]*scale);
        }
    }
    __syncthreads();

    // ---- denominator: plain sum of P from LDS ----
    float sum = 0.f;
    #pragma unroll
    for (int i=0;i<K2_;++i) sum += S[i][x];
    const float inv = 1.0f/sum;

    // ---- PV: my channel-groups {2w, 2w+1}; P read from LDS ----
    const int cg0 = w*2, cg1 = w*2 + 1;
    float4 a0 = make_float4(0.f,0.f,0.f,0.f);
    float4 a1 = make_float4(0.f,0.f,0.f,0.f);
    #pragma unroll
    for (int r=0; r<K_; ++r) {
        const uint2* row0 = vb + (size_t)cg0*PPIX_ + (size_t)(y + r)*PW_ + x;
        const uint2* row1 = vb + (size_t)cg1*PPIX_ + (size_t)(y + r)*PW_ + x;
        #pragma unroll
        for (int kx=0; kx<K_; ++kx) {
            const float p = S[r*K_+kx][x];
            uint2 u0 = row0[kx];
            uint2 u1 = row1[kx];
            a0.x = fmaf(p, __uint_as_float(u0.x << 16),        a0.x);
            a0.y = fmaf(p, __uint_as_float(u0.x & 0xffff0000u), a0.y);
            a0.z = fmaf(p, __uint_as_float(u0.y << 16),        a0.z);
            a0.w = fmaf(p, __uint_as_float(u0.y & 0xffff0000u), a0.w);
            a1.x = fmaf(p, __uint_as_float(u1.x << 16),        a1.x);
            a1.y = fmaf(p, __uint_as_float(u1.x & 0xffff0000u), a1.y);
            a1.z = fmaf(p, __uint_as_float(u1.y << 16),        a1.z);
            a1.w = fmaf(p, __uint_as_float(u1.y & 0xffff0000u), a1.w);
        }
    }
    qpl[(size_t)cg0*L_ + y*W_ + x] = make_uint2(pk2(a0.x*inv, a0.y*inv), pk2(a0.z*inv, a0.w*inv));
    qpl[(size_t)cg1*L_ + y*W_ + x] = make_uint2(pk2(a1.x*inv, a1.y*inv), pk2(a1.z*inv, a1.w*inv));
}

// ---------------- Kernel D: output projection via bf16 MFMA (64-o tiles) ----
// grid (64, 4, 2) = 512 blocks. X staging is a pure uint2 copy (attn out bf16).
__global__ __launch_bounds__(256) void out_mfma(
    const uint2* __restrict__ qt2, const unsigned* __restrict__ wb,
    const float* __restrict__ bo, float* __restrict__ out)
{
    const int b    = blockIdx.z;
    const int l0   = blockIdx.x * 64;
    const int o_t0 = blockIdx.y * 64;
    const unsigned* wbp = wb + 3*32768;
    const int tid  = threadIdx.x;
    const int lane = tid & 63, wave = tid >> 6;
    const int orow = lane & 15, kgrp = lane >> 4;

    __shared__ short Ws[64*WS_STR];    // 9.2 KB
    __shared__ short Xs[64*WS_STR];    // 9.2 KB

    f32x4 acc[4] = {};
    const int cq  = tid >> 6;
    const int lst = tid & 63;

    for (int ch = 0; ch < 4; ++ch) {
        const int c0 = ch*64;
        #pragma unroll
        for (int i = 0; i < 4; ++i) {
            int o  = i*16 + (tid>>4);
            int c4 = tid & 15;
            uint2 v = *reinterpret_cast<const uint2*>(wbp + (size_t)(o_t0 + o)*128 + (c0>>1) + c4*2);
            *reinterpret_cast<uint2*>(&Ws[o*WS_STR + c4*4]) = v;
        }
        #pragma unroll
        for (int i = 0; i < 4; ++i) {
            int c4i = i*4 + cq;
            uint2 v = qt2[(size_t)(b*64 + (c0>>2) + c4i)*L_ + l0 + lst];
            *reinterpret_cast<uint2*>(&Xs[lst*WS_STR + c4i*4]) = v;
        }
        __syncthreads();
        #pragma unroll
        for (int kk = 0; kk < 2; ++kk) {
            bf16x8 af, bfr[4];
            af = *reinterpret_cast<const bf16x8*>(&Ws[(wave*16 + orow)*WS_STR + kk*32 + kgrp*8]);
            #pragma unroll
            for (int fn = 0; fn < 4; ++fn)
                bfr[fn] = *reinterpret_cast<const bf16x8*>(&Xs[(fn*16 + orow)*WS_STR + kk*32 + kgrp*8]);
            #pragma unroll
            for (int fn = 0; fn < 4; ++fn)
                acc[fn] = __builtin_amdgcn_mfma_f32_16x16x32_bf16(af, bfr[fn], acc[fn], 0, 0, 0);
        }
        __syncthreads();
    }

    {
        const int o_base = o_t0 + wave*16 + kgrp*4;
        #pragma unroll
        for (int fn = 0; fn < 4; ++fn) {
            const int xl = fn*16 + orow;
            #pragma unroll
            for (int r = 0; r < 4; ++r)
                out[(size_t)(b*C_ + o_base + r)*L_ + l0 + xl] = acc[fn][r] + bo[o_base + r];
        }
    }
}

extern "C" void kernel_launch(void* const* d_in, const int* in_sizes, int n_in,
                              void* d_out, int out_size, void* d_ws, size_t ws_size,
                              hipStream_t stream) {
    const float* queries = (const float*)d_in[0];
    const float* keys    = (const float*)d_in[1];
    const float* values  = (const float*)d_in[2];
    const float* wq = (const float*)d_in[3];
    const float* bq = (const float*)d_in[4];
    const float* wk = (const float*)d_in[5];
    const float* bk = (const float*)d_in[6];
    const float* wv = (const float*)d_in[7];
    const float* bv = (const float*)d_in[8];
    const float* wo = (const float*)d_in[9];
    const float* bo = (const float*)d_in[10];
    float* out = (float*)d_out;

    uint2* qt2 = (uint2*)d_ws;                             // Q bf16 planar, attn out in-place
    uint2* kt2 = qt2 + (size_t)B_*HEADS_*CG_*L_;           // padded planar K (bf16 x4)
    uint2* vt2 = kt2 + PADT_;                              // padded planar V (bf16 x4)
    unsigned* wb = (unsigned*)(vt2 + PADT_);               // bf16 packed weights

    prep<<<512, 256, 0, stream>>>(wq, wk, wv, wo, wb);
    qkv_mfma<<<dim3(64, 2, 7), 256, 0, stream>>>(queries, keys, values, wb, bq, bk, bv, qt2, kt2, vt2);
    local_attn<<<1024, 256, 0, stream>>>(qt2, kt2, vt2);
    out_mfma<<<dim3(64, 4, 2), 256, 0, stream>>>(qt2, wb, bo, out);
}

// Round 14
// 52.047 us; speedup vs baseline: 1.7373x; 1.0234x over previous
//
#include <hip/hip_runtime.h>
#include <hip/hip_fp16.h>
#include <math.h>

#define B_ 2
#define C_ 256
#define H_ 64
#define W_ 64
#define L_ 4096
#define HEADS_ 8
#define DH_ 32
#define CG_ 8
#define K_ 7
#define PAD_ 3
#define K2_ 49
#define PW_ 70
#define PPIX_ 4900
#define PADT_ ((size_t)B_*HEADS_*CG_*PPIX_)    // 627200 uint2 (f16x4) per padded tensor
#define WS_STR 72                               // LDS row stride in f16 elems (144B)

typedef _Float16 f16x8 __attribute__((ext_vector_type(8)));
typedef _Float16 h2    __attribute__((ext_vector_type(2)));
typedef float    f32x4 __attribute__((ext_vector_type(4)));

__device__ inline h2 u2h(unsigned u) { union { unsigned u; h2 h; } c; c.u = u; return c.h; }
__device__ inline h2 cvt2h(float a, float b) {
    auto r = __builtin_amdgcn_cvt_pkrtz(a, b);      // __fp16 ext_vector(2)
    union { decltype(r) s; h2 d; } c; c.s = r; return c.d;
}
__device__ inline unsigned pkh(float a, float b) {
    union { h2 h; unsigned u; } c; c.h = cvt2h(a, b); return c.u;
}

// ---------------- Kernel A: weight pack (f16) ------------------------------
__global__ __launch_bounds__(256) void prep(
    const float* __restrict__ wq, const float* __restrict__ wk,
    const float* __restrict__ wv, const float* __restrict__ wo,
    unsigned* __restrict__ wb)
{
    int idx = blockIdx.x*256 + threadIdx.x;   // 0..131071
    const float* src = (idx < 32768) ? wq : (idx < 65536) ? wk : (idx < 98304) ? wv : wo;
    int off = (idx & 32767) * 2;
    wb[idx] = pkh(src[off], src[off+1]);
}

// ---------------- Kernel B: QKV projection via f16 MFMA + halo-zero slice ---
// z = 0..5: GEMM (which = z>>1, b = z&1), 128 o x 64 l per block.
// z = 6:    K/V halo zeroing. All outputs f16-packed (uint2 = 4 channels).
__global__ __launch_bounds__(256) void qkv_mfma(
    const float* __restrict__ q_in, const float* __restrict__ k_in, const float* __restrict__ v_in,
    const unsigned* __restrict__ wb,
    const float* __restrict__ bq, const float* __restrict__ bk, const float* __restrict__ bv,
    uint2* __restrict__ qt2, uint2* __restrict__ kt2, uint2* __restrict__ vt2)
{
    const int z = blockIdx.z;
    const int tid = threadIdx.x;

    if (z == 6) {
        const int flat = blockIdx.x + 64*blockIdx.y;   // 0..127
        const uint2 zz = make_uint2(0u, 0u);
        for (size_t idx = (size_t)flat*256 + tid; idx < PADT_; idx += 128*256) {
            int cell = (int)(idx % PPIX_);
            int px = cell % PW_, py = cell / PW_;
            if (px < PAD_ || px >= PW_-PAD_ || py < PAD_ || py >= PW_-PAD_) {
                kt2[idx] = zz;
                vt2[idx] = zz;
            }
        }
        return;
    }

    const int which = z >> 1;      // 0=q,1=k,2=v
    const int b = z & 1;
    const float* X = (which==0) ? q_in : (which==1 ? k_in : v_in);
    const unsigned* wbp = wb + which*32768;
    const float* bias = (which==0) ? bq : (which==1 ? bk : bv);

    const int y    = blockIdx.x;
    const int l0   = y * 64;
    const int o_t0 = blockIdx.y * 128;
    const int lane = tid & 63, wave = tid >> 6;
    const int orow = lane & 15, kgrp = lane >> 4;

    __shared__ _Float16 Ws[128*WS_STR];   // weights [o][c-chunk]  (18.4 KB)
    __shared__ _Float16 Xs[64*WS_STR];    // input^T [l][c-chunk]  (9.2 KB)

    f32x4 acc[2][4] = {};

    for (int ch = 0; ch < 4; ++ch) {
        const int c0 = ch*64;
        #pragma unroll
        for (int i = 0; i < 8; ++i) {
            int o  = i*16 + (tid>>4);
            int c4 = tid & 15;
            uint2 v = *reinterpret_cast<const uint2*>(wbp + (size_t)(o_t0 + o)*128 + (c0>>1) + c4*2);
            *reinterpret_cast<uint2*>(&Ws[o*WS_STR + c4*4]) = v;
        }
        // Xs staging: float4 along l (4 VMEM instrs/chunk), f16 transpose writes
        #pragma unroll
        for (int i = 0; i < 4; ++i) {
            int c_loc = (tid>>4) + i*16;        // 0..63
            int l4    = (tid&15)*4;             // 0,4,...,60
            float4 xv = *reinterpret_cast<const float4*>(&X[(size_t)(b*C_ + c0 + c_loc)*L_ + l0 + l4]);
            Xs[(l4+0)*WS_STR + c_loc] = (_Float16)xv.x;
            Xs[(l4+1)*WS_STR + c_loc] = (_Float16)xv.y;
            Xs[(l4+2)*WS_STR + c_loc] = (_Float16)xv.z;
            Xs[(l4+3)*WS_STR + c_loc] = (_Float16)xv.w;
        }
        __syncthreads();
        #pragma unroll
        for (int kk = 0; kk < 2; ++kk) {
            f16x8 af[2], bfr[4];
            #pragma unroll
            for (int fo = 0; fo < 2; ++fo)
                af[fo] = *reinterpret_cast<const f16x8*>(&Ws[(wave*32 + fo*16 + orow)*WS_STR + kk*32 + kgrp*8]);
            #pragma unroll
            for (int fn = 0; fn < 4; ++fn)
                bfr[fn] = *reinterpret_cast<const f16x8*>(&Xs[(fn*16 + orow)*WS_STR + kk*32 + kgrp*8]);
            #pragma unroll
            for (int fo = 0; fo < 2; ++fo)
                #pragma unroll
                for (int fn = 0; fn < 4; ++fn)
                    acc[fo][fn] = __builtin_amdgcn_mfma_f32_16x16x32_f16(af[fo], bfr[fn], acc[fo][fn], 0, 0, 0);
        }
        __syncthreads();
    }

    #pragma unroll
    for (int fo = 0; fo < 2; ++fo) {
        const int og = o_t0 + wave*32 + fo*16 + kgrp*4;
        const float4 b4 = *reinterpret_cast<const float4*>(&bias[og]);
        const size_t p = (size_t)(b*64 + (og >> 2));   // plane index
        #pragma unroll
        for (int fn = 0; fn < 4; ++fn) {
            const int xl = fn*16 + orow;
            uint2 r = make_uint2(pkh(acc[fo][fn][0] + b4.x, acc[fo][fn][1] + b4.y),
                                 pkh(acc[fo][fn][2] + b4.z, acc[fo][fn][3] + b4.w));
            if (which == 0) {
                qt2[p*L_ + l0 + xl] = r;
            } else {
                uint2* dst = (which==1) ? kt2 : vt2;
                dst[p*PPIX_ + (size_t)(y+PAD_)*PW_ + (xl+PAD_)] = r;
            }
        }
    }
}

// ---------------- Kernel C: 7x7 local attention, f16, dot2/pk_fma -----------
// Block = (plane=b*8+h, image row y), 256 threads (4 waves), grid 1024.
// QK: v_dot2_f32_f16 (f32 accumulate). PV: packed f16 fma per tap, f16 row
// partials upconverted to f32 every 7 taps (bounds f16 accum error).
__global__ __launch_bounds__(256) void local_attn(
    uint2* __restrict__ qt2, const uint2* __restrict__ kt2, const uint2* __restrict__ vt2)
{
    const int tid = threadIdx.x;
    const int w = tid >> 6, x = tid & 63;
    const int bid = blockIdx.x;
    const int plane = bid & 15;      // plane -> XCD plane%8: K/V L2-resident per XCD
    const int y = bid >> 4;          // 0..63

    const uint2* kb = kt2 + (size_t)plane*CG_*PPIX_;
    const uint2* vb = vt2 + (size_t)plane*CG_*PPIX_;
    uint2* qpl = qt2 + (size_t)plane*CG_*L_;

    __shared__ float S[K2_][64];     // holds P = exp(logit*scale); 12.25 KB

    const float scale = 0.0625f; // 1/sqrt(256)

    // ---- QK: my window rows r = w and w+4 (v_dot2_f32_f16) ----
    float lg[2][K_] = {};
    #pragma unroll
    for (int cg=0; cg<CG_; ++cg) {
        uint2 qu = qpl[(size_t)cg*L_ + y*W_ + x];
        const h2 q01 = u2h(qu.x), q23 = u2h(qu.y);
        #pragma unroll
        for (int rr=0; rr<2; ++rr) {
            const int r = w + rr*4;
            if (r > 6) continue;                  // only w=3,rr=1 skips (uniform)
            const uint2* row = kb + (size_t)cg*PPIX_ + (size_t)(y + r)*PW_ + x;
            #pragma unroll
            for (int kx=0; kx<K_; ++kx) {
                uint2 kk = row[kx];
                lg[rr][kx] = __builtin_amdgcn_fdot2(q01, u2h(kk.x), lg[rr][kx], false);
                lg[rr][kx] = __builtin_amdgcn_fdot2(q23, u2h(kk.y), lg[rr][kx], false);
            }
        }
    }
    #pragma unroll
    for (int rr=0; rr<2; ++rr) {
        const int r = w + rr*4;
        if (r <= 6) {
            #pragma unroll
            for (int kx=0; kx<K_; ++kx) S[r*K_+kx][x] = __expf(lg[rr][kx]*scale);
        }
    }
    __syncthreads();

    // ---- denominator: plain sum of P from LDS ----
    float sum = 0.f;
    #pragma unroll
    for (int i=0;i<K2_;++i) sum += S[i][x];
    const float inv = 1.0f/sum;

    // ---- PV: my channel-groups {2w, 2w+1}; packed f16 fma, f32 row carry ----
    const int cg0 = w*2, cg1 = w*2 + 1;
    float4 a0 = make_float4(0.f,0.f,0.f,0.f);
    float4 a1 = make_float4(0.f,0.f,0.f,0.f);
    #pragma unroll
    for (int r=0; r<K_; ++r) {
        const uint2* row0 = vb + (size_t)cg0*PPIX_ + (size_t)(y + r)*PW_ + x;
        const uint2* row1 = vb + (size_t)cg1*PPIX_ + (size_t)(y + r)*PW_ + x;
        h2 ra0 = (h2)0, ra1 = (h2)0, rb0 = (h2)0, rb1 = (h2)0;
        #pragma unroll
        for (int kx=0; kx<K_; ++kx) {
            const float p = S[r*K_+kx][x];
            const h2 p2 = cvt2h(p, p);
            uint2 u0 = row0[kx];
            uint2 u1 = row1[kx];
            ra0 += p2 * u2h(u0.x);
            ra1 += p2 * u2h(u0.y);
            rb0 += p2 * u2h(u1.x);
            rb1 += p2 * u2h(u1.y);
        }
        a0.x += (float)ra0[0]; a0.y += (float)ra0[1];
        a0.z += (float)ra1[0]; a0.w += (float)ra1[1];
        a1.x += (float)rb0[0]; a1.y += (float)rb0[1];
        a1.z += (float)rb1[0]; a1.w += (float)rb1[1];
    }
    qpl[(size_t)cg0*L_ + y*W_ + x] = make_uint2(pkh(a0.x*inv, a0.y*inv), pkh(a0.z*inv, a0.w*inv));
    qpl[(size_t)cg1*L_ + y*W_ + x] = make_uint2(pkh(a1.x*inv, a1.y*inv), pkh(a1.z*inv, a1.w*inv));
}

// ---------------- Kernel D: output projection via f16 MFMA (64-o tiles) -----
// grid (64, 4, 2) = 512 blocks. X staging is a pure uint2 copy.
__global__ __launch_bounds__(256) void out_mfma(
    const uint2* __restrict__ qt2, const unsigned* __restrict__ wb,
    const float* __restrict__ bo, float* __restrict__ out)
{
    const int b    = blockIdx.z;
    const int l0   = blockIdx.x * 64;
    const int o_t0 = blockIdx.y * 64;
    const unsigned* wbp = wb + 3*32768;
    const int tid  = threadIdx.x;
    const int lane = tid & 63, wave = tid >> 6;
    const int orow = lane & 15, kgrp = lane >> 4;

    __shared__ _Float16 Ws[64*WS_STR];    // 9.2 KB
    __shared__ _Float16 Xs[64*WS_STR];    // 9.2 KB

    f32x4 acc[4] = {};
    const int cq  = tid >> 6;
    const int lst = tid & 63;

    for (int ch = 0; ch < 4; ++ch) {
        const int c0 = ch*64;
        #pragma unroll
        for (int i = 0; i < 4; ++i) {
            int o  = i*16 + (tid>>4);
            int c4 = tid & 15;
            uint2 v = *reinterpret_cast<const uint2*>(wbp + (size_t)(o_t0 + o)*128 + (c0>>1) + c4*2);
            *reinterpret_cast<uint2*>(&Ws[o*WS_STR + c4*4]) = v;
        }
        #pragma unroll
        for (int i = 0; i < 4; ++i) {
            int c4i = i*4 + cq;
            uint2 v = qt2[(size_t)(b*64 + (c0>>2) + c4i)*L_ + l0 + lst];
            *reinterpret_cast<uint2*>(&Xs[lst*WS_STR + c4i*4]) = v;
        }
        __syncthreads();
        #pragma unroll
        for (int kk = 0; kk < 2; ++kk) {
            f16x8 af, bfr[4];
            af = *reinterpret_cast<const f16x8*>(&Ws[(wave*16 + orow)*WS_STR + kk*32 + kgrp*8]);
            #pragma unroll
            for (int fn = 0; fn < 4; ++fn)
                bfr[fn] = *reinterpret_cast<const f16x8*>(&Xs[(fn*16 + orow)*WS_STR + kk*32 + kgrp*8]);
            #pragma unroll
            for (int fn = 0; fn < 4; ++fn)
                acc[fn] = __builtin_amdgcn_mfma_f32_16x16x32_f16(af, bfr[fn], acc[fn], 0, 0, 0);
        }
        __syncthreads();
    }

    {
        const int o_base = o_t0 + wave*16 + kgrp*4;
        #pragma unroll
        for (int fn = 0; fn < 4; ++fn) {
            const int xl = fn*16 + orow;
            #pragma unroll
            for (int r = 0; r < 4; ++r)
                out[(size_t)(b*C_ + o_base + r)*L_ + l0 + xl] = acc[fn][r] + bo[o_base + r];
        }
    }
}

extern "C" void kernel_launch(void* const* d_in, const int* in_sizes, int n_in,
                              void* d_out, int out_size, void* d_ws, size_t ws_size,
                              hipStream_t stream) {
    const float* queries = (const float*)d_in[0];
    const float* keys    = (const float*)d_in[1];
    const float* values  = (const float*)d_in[2];
    const float* wq = (const float*)d_in[3];
    const float* bq = (const float*)d_in[4];
    const float* wk = (const float*)d_in[5];
    const float* bk = (const float*)d_in[6];
    const float* wv = (const float*)d_in[7];
    const float* bv = (const float*)d_in[8];
    const float* wo = (const float*)d_in[9];
    const float* bo = (const float*)d_in[10];
    float* out = (float*)d_out;

    uint2* qt2 = (uint2*)d_ws;                             // Q f16 planar, attn out in-place
    uint2* kt2 = qt2 + (size_t)B_*HEADS_*CG_*L_;           // padded planar K (f16 x4)
    uint2* vt2 = kt2 + PADT_;                              // padded planar V (f16 x4)
    unsigned* wb = (unsigned*)(vt2 + PADT_);               // f16 packed weights

    prep<<<512, 256, 0, stream>>>(wq, wk, wv, wo, wb);
    qkv_mfma<<<dim3(64, 2, 7), 256, 0, stream>>>(queries, keys, values, wb, bq, bk, bv, qt2, kt2, vt2);
    local_attn<<<1024, 256, 0, stream>>>(qt2, kt2, vt2);
    out_mfma<<<dim3(64, 4, 2), 256, 0, stream>>>(qt2, wb, bo, out);
}